// Round 4
// baseline (137.456 us; speedup 1.0000x reference)
//
#include <hip/hip_runtime.h>

// Problem constants
#define DIM 128
#define HID 256
#define K2LE 2.885390081777927f   // 2*log2(e): tanh(x) = 1 - 2/(exp2(K2LE*x)+1)
#define NTILES 16                 // HID / 16
#define RPB 32                    // rays per block (4 waves x 8 kept rays)
#define BFPAD 136                 // bf16 LDS row stride

typedef __attribute__((ext_vector_type(8))) short bf16x8;   // 8 bf16 = 4 VGPRs
typedef __attribute__((ext_vector_type(4))) float f32x4;

__device__ __forceinline__ unsigned short f2bf(float f) {
    union { float f; unsigned u; } x; x.f = f;
    unsigned r = x.u + 0x7fffu + ((x.u >> 16) & 1u);   // RNE
    return (unsigned short)(r >> 16);
}

__device__ __forceinline__ float sigmoid_fast(float x) {
    float t = __builtin_amdgcn_exp2f(-x * 1.4426950408889634f);
    return __builtin_amdgcn_rcpf(1.0f + t);
}

// ---------------------------------------------------------------------------
// Prep: c2[j] = K2LE*(pivot@W1 + b1)[j]  (f32, block 0)
//       W1f   = bf16(K2LE*W1) in MFMA B-fragment order:
//               entry e = nt*256 + kk*64 + q*16 + m  holds
//               W1[kk*32+q*8+j][nt*16+m], j=0..7  (16 B per entry)
// ---------------------------------------------------------------------------
__global__ void k_prep(const float* __restrict__ pivot,
                       const float* __restrict__ W1,
                       const float* __restrict__ b1,
                       float* __restrict__ c2,
                       uint4* __restrict__ W1f) {
    const int tid = threadIdx.x;
    if (blockIdx.x == 0) {
        float a = b1[tid];
#pragma unroll 8
        for (int d = 0; d < DIM; ++d) a = fmaf(pivot[d], W1[d * HID + tid], a);
        c2[tid] = K2LE * a;
    }
    const int e  = blockIdx.x * 256 + tid;
    const int m  = e & 15;
    const int q  = (e >> 4) & 3;
    const int kk = (e >> 6) & 3;
    const int nt = e >> 8;
    const int n  = nt * 16 + m;
    const int k0 = kk * 32 + q * 8;
    unsigned w[4];
#pragma unroll
    for (int p = 0; p < 4; ++p) {
        unsigned lo = f2bf(W1[(k0 + 2 * p    ) * HID + n] * K2LE);
        unsigned hi = f2bf(W1[(k0 + 2 * p + 1) * HID + n] * K2LE);
        w[p] = lo | (hi << 16);
    }
    W1f[e] = make_uint4(w[0], w[1], w[2], w[3]);
}

// ---------------------------------------------------------------------------
// Main: 1024 blocks x 256 threads. Block owns 32 rays; wave pair (p = wave>>1)
// shares a 16-ray MFMA tile; each wave KEEPS 8 rays (2 of 4 C-regs) so the
// iterate phase runs 4096 waves = 4 waves/SIMD.
// ---------------------------------------------------------------------------
__global__ __launch_bounds__(256, 4) void k_main(
    const float* __restrict__ r,      // [B, 128]
    const float* __restrict__ s,      // [B]
    const float* __restrict__ pivot,  // [128]
    const float* __restrict__ w2,     // [256]
    const float* __restrict__ b2,     // [1]
    const int* __restrict__ n_iter_p, // [1]
    const float* __restrict__ c2,     // [256] K2LE*(pivot@W1+b1)
    const uint4* __restrict__ W1f,    // frag-ordered bf16 K2LE*W1
    float* __restrict__ out)          // [B, 128]
{
    __shared__ unsigned short rnbf[RPB][BFPAD];   // bf16 rn  (8.7 KB)
    __shared__ float rnf[RPB][DIM];               // f32 rn   (16 KB)
    __shared__ float alpha_s[RPB];

    const int tid  = threadIdx.x;
    const int lane = tid & 63;
    const int wave = tid >> 6;          // 0..3
    const int pr   = wave >> 1;         // pair index (16-ray tile)
    const int par  = wave & 1;          // which C-reg pair this wave keeps
    const int m    = lane & 15;         // MFMA col-in-tile / A-row
    const int q    = lane >> 4;         // MFMA quad
    const int rowblk = blockIdx.x * RPB;
    const int n_iter = *n_iter_p;

    // ---- Phase 1: wave loads+normalizes block-local rays [wave*8, wave*8+8) ----
#pragma unroll
    for (int t = 0; t < 8; ++t) {
        const int lr = wave * 8 + t;
        float2 v = *(const float2*)&r[(rowblk + lr) * DIM + lane * 2];
        float ss = v.x * v.x + v.y * v.y;
#pragma unroll
        for (int msk = 32; msk >= 1; msk >>= 1) ss += __shfl_xor(ss, msk, 64);
        float inv = __builtin_amdgcn_rsqf(ss);
        float2 rn; rn.x = v.x * inv; rn.y = v.y * inv;
        *(float2*)&rnf[lr][lane * 2] = rn;
        unsigned pack = (unsigned)f2bf(rn.x) | ((unsigned)f2bf(rn.y) << 16);
        *(unsigned*)&rnbf[lr][lane * 2] = pack;
    }
    __syncthreads();

    // ---- Phase 2: 16-ray x 256-col GEMM via MFMA; keep rays reg par*2+{0,1} ----
    bf16x8 afrag[4];
#pragma unroll
    for (int kk = 0; kk < 4; ++kk)
        afrag[kk] = *(const bf16x8*)&rnbf[pr * 16 + m][kk * 32 + q * 8];

    const bf16x8* __restrict__ wf = (const bf16x8*)W1f;
    const int fb = q * 16 + m;
    float gA[NTILES], gB[NTILES];
#pragma unroll
    for (int nt = 0; nt < NTILES; ++nt) {
        f32x4 a = {0.f, 0.f, 0.f, 0.f};
#pragma unroll
        for (int kk = 0; kk < 4; ++kk)
            a = __builtin_amdgcn_mfma_f32_16x16x32_bf16(
                    afrag[kk], wf[nt * 256 + kk * 64 + fb], a, 0, 0, 0);
        gA[nt] = a[par * 2 + 0];   // local ray pr*16 + q*4 + par*2 + 0
        gB[nt] = a[par * 2 + 1];   // local ray pr*16 + q*4 + par*2 + 1
    }

    // ---- Per-lane column params (col = nt*16 + m) ----
    float w2f[NTILES], c2f[NTILES];
#pragma unroll
    for (int nt = 0; nt < NTILES; ++nt) {
        w2f[nt] = w2[nt * 16 + m];
        c2f[nt] = c2[nt * 16 + m];
    }
    float S = 0.f;
#pragma unroll
    for (int nt = 0; nt < NTILES; ++nt) S += w2f[nt];
#pragma unroll
    for (int msk = 1; msk <= 8; msk <<= 1) S += __shfl_xor(S, msk, 64);
    const float C0 = K2LE * (S + b2[0]);

    // ---- Phase 3: n_iter ray-march steps (2 rays/lane, 16 cols/lane) ----
    float alphaA = 0.f, alphaB = 0.f;
    for (int it = 0; it < n_iter; ++it) {
        float pA = 0.f, pB = 0.f;
#pragma unroll
        for (int nt = 0; nt < NTILES; ++nt) {
            float uA = __builtin_amdgcn_rcpf(__builtin_amdgcn_exp2f(fmaf(alphaA, gA[nt], c2f[nt])) + 1.0f);
            float uB = __builtin_amdgcn_rcpf(__builtin_amdgcn_exp2f(fmaf(alphaB, gB[nt], c2f[nt])) + 1.0f);
            pA = fmaf(w2f[nt], uA, pA);
            pB = fmaf(w2f[nt], uB, pB);
        }
#pragma unroll
        for (int msk = 1; msk <= 8; msk <<= 1) {
            pA += __shfl_xor(pA, msk, 64);
            pB += __shfl_xor(pB, msk, 64);
        }
        float vA = __builtin_amdgcn_rcpf(__builtin_amdgcn_exp2f(fmaf(-2.0f * K2LE, pA, C0)) + 1.0f);
        float vB = __builtin_amdgcn_rcpf(__builtin_amdgcn_exp2f(fmaf(-2.0f * K2LE, pB, C0)) + 1.0f);
        alphaA += fmaf(-0.1f, vA, 0.1f);
        alphaB += fmaf(-0.1f, vB, 0.1f);
    }

    // ---- Publish alpha (uniform across the 16 m-lanes of each quad) ----
    if (m == 0) {
        alpha_s[pr * 16 + q * 4 + par * 2 + 0] = alphaA;
        alpha_s[pr * 16 + q * 4 + par * 2 + 1] = alphaB;
    }
    __syncthreads();

    // ---- Phase 4: out[row] = pivot + sigmoid(s[row])*alpha*rn (wave's 8 rays) ----
    const float2 pv = *(const float2*)&pivot[lane * 2];
#pragma unroll
    for (int t = 0; t < 8; ++t) {
        const int lr  = wave * 8 + t;
        const int row = rowblk + lr;
        const float scale = sigmoid_fast(s[row]) * alpha_s[lr];
        float2 rn = *(const float2*)&rnf[lr][lane * 2];
        float2 o;
        o.x = fmaf(scale, rn.x, pv.x);
        o.y = fmaf(scale, rn.y, pv.y);
        *(float2*)&out[row * DIM + lane * 2] = o;
    }
}

extern "C" void kernel_launch(void* const* d_in, const int* in_sizes, int n_in,
                              void* d_out, int out_size, void* d_ws, size_t ws_size,
                              hipStream_t stream) {
    const float* r      = (const float*)d_in[0];
    const float* s      = (const float*)d_in[1];
    const float* pivot  = (const float*)d_in[2];
    const float* W1     = (const float*)d_in[3];
    const float* b1     = (const float*)d_in[4];
    const float* w2     = (const float*)d_in[5];
    const float* b2     = (const float*)d_in[6];
    const int*   n_iter = (const int*)d_in[7];
    float* out = (float*)d_out;

    float* c2  = (float*)d_ws;                       // 256 f32
    uint4* W1f = (uint4*)((char*)d_ws + 4096);       // 64 KB frag-ordered bf16

    const int B = in_sizes[0] / DIM;  // 32768

    k_prep<<<16, 256, 0, stream>>>(pivot, W1, b1, c2, W1f);
    k_main<<<B / RPB, 256, 0, stream>>>(r, s, pivot, w2, b2, n_iter, c2, W1f, out);
}

// Round 5
// 131.097 us; speedup vs baseline: 1.0485x; 1.0485x over previous
//
#include <hip/hip_runtime.h>

// Problem constants
#define DIM 128
#define HID 256
#define K2LE 2.885390081777927f   // 2*log2(e): tanh(x) = 1 - 2/(exp2(K2LE*x)+1)
#define NTILES 16                 // HID / 16
#define RPB 32                    // rays per block (4 waves x 8 kept rays)
#define BFPAD 136                 // bf16 LDS row stride

typedef __attribute__((ext_vector_type(8))) short bf16x8;   // 8 bf16 = 4 VGPRs
typedef __attribute__((ext_vector_type(4))) float f32x4;

__device__ __forceinline__ unsigned short f2bf(float f) {
    union { float f; unsigned u; } x; x.f = f;
    unsigned r = x.u + 0x7fffu + ((x.u >> 16) & 1u);   // RNE
    return (unsigned short)(r >> 16);
}

__device__ __forceinline__ float sigmoid_fast(float x) {
    float t = __builtin_amdgcn_exp2f(-x * 1.4426950408889634f);
    return __builtin_amdgcn_rcpf(1.0f + t);
}

// All-reduce sum across the 16 lanes of a DPP row (lanes q*16..q*16+15)
// using VALU-pipe DPP ops only — no LDS, ~4cy/step vs ~120cy ds_swizzle.
// Steps: quad swap(1,0,3,2)=0xB1, quad swap(2,3,0,1)=0x4E, row_ror:4=0x124,
// row_ror:8=0x128. After all 4 adds every lane holds the 16-lane sum.
__device__ __forceinline__ float row16_allreduce(float x) {
    int t;
    t = __builtin_amdgcn_update_dpp(0, __float_as_int(x), 0xB1, 0xf, 0xf, true);
    x += __int_as_float(t);
    t = __builtin_amdgcn_update_dpp(0, __float_as_int(x), 0x4E, 0xf, 0xf, true);
    x += __int_as_float(t);
    t = __builtin_amdgcn_update_dpp(0, __float_as_int(x), 0x124, 0xf, 0xf, true);
    x += __int_as_float(t);
    t = __builtin_amdgcn_update_dpp(0, __float_as_int(x), 0x128, 0xf, 0xf, true);
    x += __int_as_float(t);
    return x;
}

// ---------------------------------------------------------------------------
// Prep: c2[j] = K2LE*(pivot@W1 + b1)[j]  (f32, block 0)
//       W1f   = bf16(K2LE*W1) in MFMA B-fragment order:
//               entry e = nt*256 + kk*64 + q*16 + m  holds
//               W1[kk*32+q*8+j][nt*16+m], j=0..7  (16 B per entry)
// ---------------------------------------------------------------------------
__global__ void k_prep(const float* __restrict__ pivot,
                       const float* __restrict__ W1,
                       const float* __restrict__ b1,
                       float* __restrict__ c2,
                       uint4* __restrict__ W1f) {
    const int tid = threadIdx.x;
    if (blockIdx.x == 0) {
        float a = b1[tid];
#pragma unroll 8
        for (int d = 0; d < DIM; ++d) a = fmaf(pivot[d], W1[d * HID + tid], a);
        c2[tid] = K2LE * a;
    }
    const int e  = blockIdx.x * 256 + tid;
    const int m  = e & 15;
    const int q  = (e >> 4) & 3;
    const int kk = (e >> 6) & 3;
    const int nt = e >> 8;
    const int n  = nt * 16 + m;
    const int k0 = kk * 32 + q * 8;
    unsigned w[4];
#pragma unroll
    for (int p = 0; p < 4; ++p) {
        unsigned lo = f2bf(W1[(k0 + 2 * p    ) * HID + n] * K2LE);
        unsigned hi = f2bf(W1[(k0 + 2 * p + 1) * HID + n] * K2LE);
        w[p] = lo | (hi << 16);
    }
    W1f[e] = make_uint4(w[0], w[1], w[2], w[3]);
}

// ---------------------------------------------------------------------------
// Main: 1024 blocks x 256 threads. Wave pair shares a 16-ray MFMA tile; each
// wave keeps 8 rays (2 of 4 C-regs). 4096 waves = 4 waves/SIMD.
// ---------------------------------------------------------------------------
__global__ __launch_bounds__(256, 4) void k_main(
    const float* __restrict__ r,      // [B, 128]
    const float* __restrict__ s,      // [B]
    const float* __restrict__ pivot,  // [128]
    const float* __restrict__ w2,     // [256]
    const float* __restrict__ b2,     // [1]
    const int* __restrict__ n_iter_p, // [1]
    const float* __restrict__ c2,     // [256] K2LE*(pivot@W1+b1)
    const uint4* __restrict__ W1f,    // frag-ordered bf16 K2LE*W1
    float* __restrict__ out)          // [B, 128]
{
    __shared__ unsigned short rnbf[RPB][BFPAD];   // bf16 rn  (8.7 KB)
    __shared__ float rnf[RPB][DIM];               // f32 rn   (16 KB)
    __shared__ float alpha_s[RPB];

    const int tid  = threadIdx.x;
    const int lane = tid & 63;
    const int wave = tid >> 6;          // 0..3
    const int pr   = wave >> 1;         // pair index (16-ray tile)
    const int par  = wave & 1;          // which C-reg pair this wave keeps
    const int m    = lane & 15;         // MFMA col-in-tile / A-row
    const int q    = lane >> 4;         // MFMA quad
    const int rowblk = blockIdx.x * RPB;
    const int n_iter = *n_iter_p;

    // ---- Phase 1: wave loads+normalizes block-local rays [wave*8, wave*8+8) ----
#pragma unroll
    for (int t = 0; t < 8; ++t) {
        const int lr = wave * 8 + t;
        float2 v = *(const float2*)&r[(rowblk + lr) * DIM + lane * 2];
        float ss = v.x * v.x + v.y * v.y;
#pragma unroll
        for (int msk = 32; msk >= 1; msk >>= 1) ss += __shfl_xor(ss, msk, 64);
        float inv = __builtin_amdgcn_rsqf(ss);
        float2 rn; rn.x = v.x * inv; rn.y = v.y * inv;
        *(float2*)&rnf[lr][lane * 2] = rn;
        unsigned pack = (unsigned)f2bf(rn.x) | ((unsigned)f2bf(rn.y) << 16);
        *(unsigned*)&rnbf[lr][lane * 2] = pack;
    }
    __syncthreads();

    // ---- Phase 2: 16-ray x 256-col GEMM via MFMA; keep rays reg par*2+{0,1} ----
    bf16x8 afrag[4];
#pragma unroll
    for (int kk = 0; kk < 4; ++kk)
        afrag[kk] = *(const bf16x8*)&rnbf[pr * 16 + m][kk * 32 + q * 8];

    const bf16x8* __restrict__ wf = (const bf16x8*)W1f;
    const int fb = q * 16 + m;
    float gA[NTILES], gB[NTILES];
#pragma unroll
    for (int nt = 0; nt < NTILES; ++nt) {
        f32x4 a = {0.f, 0.f, 0.f, 0.f};
#pragma unroll
        for (int kk = 0; kk < 4; ++kk)
            a = __builtin_amdgcn_mfma_f32_16x16x32_bf16(
                    afrag[kk], wf[nt * 256 + kk * 64 + fb], a, 0, 0, 0);
        gA[nt] = a[par * 2 + 0];   // local ray pr*16 + q*4 + par*2 + 0
        gB[nt] = a[par * 2 + 1];   // local ray pr*16 + q*4 + par*2 + 1
    }

    // ---- Per-lane column params (col = nt*16 + m) ----
    float w2f[NTILES], c2f[NTILES];
#pragma unroll
    for (int nt = 0; nt < NTILES; ++nt) {
        w2f[nt] = w2[nt * 16 + m];
        c2f[nt] = c2[nt * 16 + m];
    }
    float S = 0.f;
#pragma unroll
    for (int nt = 0; nt < NTILES; ++nt) S += w2f[nt];
    S = row16_allreduce(S);
    const float C0 = K2LE * (S + b2[0]);

    // ---- Phase 3: n_iter ray-march steps (2 rays/lane, 16 cols/lane) ----
    float alphaA = 0.f, alphaB = 0.f;
    for (int it = 0; it < n_iter; ++it) {
        float pA = 0.f, pB = 0.f;
#pragma unroll
        for (int nt = 0; nt < NTILES; ++nt) {
            float uA = __builtin_amdgcn_rcpf(__builtin_amdgcn_exp2f(fmaf(alphaA, gA[nt], c2f[nt])) + 1.0f);
            float uB = __builtin_amdgcn_rcpf(__builtin_amdgcn_exp2f(fmaf(alphaB, gB[nt], c2f[nt])) + 1.0f);
            pA = fmaf(w2f[nt], uA, pA);
            pB = fmaf(w2f[nt], uB, pB);
        }
        pA = row16_allreduce(pA);   // DPP, VALU-pipe only — no LDS on critical path
        pB = row16_allreduce(pB);
        float vA = __builtin_amdgcn_rcpf(__builtin_amdgcn_exp2f(fmaf(-2.0f * K2LE, pA, C0)) + 1.0f);
        float vB = __builtin_amdgcn_rcpf(__builtin_amdgcn_exp2f(fmaf(-2.0f * K2LE, pB, C0)) + 1.0f);
        alphaA += fmaf(-0.1f, vA, 0.1f);
        alphaB += fmaf(-0.1f, vB, 0.1f);
    }

    // ---- Publish alpha (uniform across the 16 m-lanes of each quad) ----
    if (m == 0) {
        alpha_s[pr * 16 + q * 4 + par * 2 + 0] = alphaA;
        alpha_s[pr * 16 + q * 4 + par * 2 + 1] = alphaB;
    }
    __syncthreads();

    // ---- Phase 4: out[row] = pivot + sigmoid(s[row])*alpha*rn (wave's 8 rays) ----
    const float2 pv = *(const float2*)&pivot[lane * 2];
#pragma unroll
    for (int t = 0; t < 8; ++t) {
        const int lr  = wave * 8 + t;
        const int row = rowblk + lr;
        const float scale = sigmoid_fast(s[row]) * alpha_s[lr];
        float2 rn = *(const float2*)&rnf[lr][lane * 2];
        float2 o;
        o.x = fmaf(scale, rn.x, pv.x);
        o.y = fmaf(scale, rn.y, pv.y);
        *(float2*)&out[row * DIM + lane * 2] = o;
    }
}

extern "C" void kernel_launch(void* const* d_in, const int* in_sizes, int n_in,
                              void* d_out, int out_size, void* d_ws, size_t ws_size,
                              hipStream_t stream) {
    const float* r      = (const float*)d_in[0];
    const float* s      = (const float*)d_in[1];
    const float* pivot  = (const float*)d_in[2];
    const float* W1     = (const float*)d_in[3];
    const float* b1     = (const float*)d_in[4];
    const float* w2     = (const float*)d_in[5];
    const float* b2     = (const float*)d_in[6];
    const int*   n_iter = (const int*)d_in[7];
    float* out = (float*)d_out;

    float* c2  = (float*)d_ws;                       // 256 f32
    uint4* W1f = (uint4*)((char*)d_ws + 4096);       // 64 KB frag-ordered bf16

    const int B = in_sizes[0] / DIM;  // 32768

    k_prep<<<16, 256, 0, stream>>>(pivot, W1, b1, c2, W1f);
    k_main<<<B / RPB, 256, 0, stream>>>(r, s, pivot, w2, b2, n_iter, c2, W1f, out);
}